// Round 16
// baseline (251.258 us; speedup 1.0000x reference)
//
#include <hip/hip_runtime.h>

// Problem constants
#define BDIM   16
#define PDIM   12
#define TDIM   4096
#define WINW   41
#define PADW   20
#define DDIM   492      // P*WIN
#define KCODES 1024

#define KS32   32                   // K-steps in the tile LAYOUT
#define KSU    31                   // K-steps actually USED (step 31 all-zero)
#define NT32   32                   // code tiles of 32 -> 1024
#define NT32_BYTES (KS32 * 64 * 8)  // 16 KiB per code tile

#define WAVES      8                 // 512-thread blocks (R5-R15: best shape)
#define ROWS_WAVE  32
#define BMROWS     (WAVES * ROWS_WAVE)   // 256 rows per block
#define MROWS      (BDIM * TDIM)         // 65536
#define NBLK       (MROWS / BMROWS)      // 256 = 1 block/CU

#define NBUF   6                    // 96 KiB staging LDS
#define DEPTH  4                    // prefetch distance

typedef __attribute__((ext_vector_type(16))) float f32x16;

__device__ __forceinline__ unsigned int pack4_fp8(float a, float b, float c, float d) {
    int v = 0;
    v = __builtin_amdgcn_cvt_pk_fp8_f32(a, b, v, false);
    v = __builtin_amdgcn_cvt_pk_fp8_f32(c, d, v, true);
    return (unsigned int)v;
}

__global__ __launch_bounds__(256) void prep_bfrag_k(const float* __restrict__ cb,
                                                    unsigned long long* __restrict__ bfrag) {
    int idx  = blockIdx.x * 256 + threadIdx.x;
    int lane = idx & 63;
    int ks   = (idx >> 6) & (KS32 - 1);
    int nt   = idx >> 11;
    int n    = nt * 32 + (lane & 31);
    int hi2  = lane >> 5;
    float v[8];
#pragma unroll
    for (int j = 0; j < 8; ++j) {
        int k = ks * 16 + hi2 * 8 + j;
        v[j] = (k < DDIM) ? cb[n * DDIM + k] : 0.f;
    }
    unsigned int lo = pack4_fp8(v[0], v[1], v[2], v[3]);
    unsigned int hi = pack4_fp8(v[4], v[5], v[6], v[7]);
    bfrag[idx] = ((unsigned long long)hi << 32) | lo;
}

__global__ __launch_bounds__(64) void prep_cnorm_k(const float* __restrict__ cb,
                                                   float* __restrict__ cnorm) {
    int n = blockIdx.x;
    int lane = threadIdx.x;
    float s = 0.f;
    for (int d = lane; d < DDIM; d += 64) { float c = cb[n * DDIM + d]; s += c * c; }
#pragma unroll
    for (int m = 1; m < 64; m <<= 1) s += __shfl_xor(s, m, 64);
    if (lane == 0) cnorm[n] = s;
}

__global__ __launch_bounds__(256) void xsq_k(const float* __restrict__ x,
                                             float* __restrict__ xsq_part) {
    float s = 0.f;
    for (int i = blockIdx.x * 256 + threadIdx.x; i < BDIM * PDIM * TDIM; i += 256 * 256) {
        int tt = i & (TDIM - 1);
        int mult = WINW - max(0, PADW - tt) - max(0, tt - (TDIM - 1 - PADW));
        float v = x[i];
        s += (float)mult * v * v;
    }
#pragma unroll
    for (int m = 1; m < 64; m <<= 1) s += __shfl_xor(s, m, 64);
    __shared__ float sm[4];
    if ((threadIdx.x & 63) == 0) sm[threadIdx.x >> 6] = s;
    __syncthreads();
    if (threadIdx.x == 0) xsq_part[blockIdx.x] = sm[0] + sm[1] + sm[2] + sm[3];
}

__device__ __forceinline__ void stage_nt(const unsigned char* __restrict__ bfrag,
                                         unsigned char* dst, int nt, int wave, int lane) {
    const unsigned char* g = bfrag + (size_t)nt * NT32_BYTES;
#pragma unroll
    for (int it = 0; it < 2; ++it) {
        int off = wave * 2048 + it * 1024;
        __builtin_amdgcn_global_load_lds(
            (const __attribute__((address_space(1))) unsigned int*)(g + off + lane * 16),
            (__attribute__((address_space(3))) unsigned int*)(dst + off),
            16, 0, 0);
    }
}

// ABLATION (R16). V0 = real R14 kernel (feeds output). V1 = ds_reads issued
// but MFMA uses afr for B (removes read->MFMA lgkmcnt dep; keeps staging +
// barriers + LDS issue load). V3 = all 6 tiles staged once, NO barriers/vmcnt
// in loop (removes sync; keeps read->MFMA dep). V5 = no reads at all (pure
// MFMA pipe floor + bs updates). V1/V3/V5 write to dummy buffers.
template<int V>
__global__ __launch_bounds__(512)
void vq_main_k(const float* __restrict__ x,
               const unsigned char* __restrict__ bfrag,
               const float* __restrict__ cnorm,
               float* __restrict__ bpart) {
    __shared__ __align__(16) unsigned char smem[NBUF][NT32_BYTES];   // 96 KiB
    __shared__ float sb_lds[KCODES];                                 // 4 KiB
    __shared__ float gsum[2 * WAVES];

    const int lane = threadIdx.x & 63;
    const int wave = threadIdx.x >> 6;
    const int col  = lane & 31;
    const int hi2  = lane >> 5;
    const int rowbase = blockIdx.x * BMROWS + wave * ROWS_WAVE;

    if (V == 3 || V == 5) {
#pragma unroll
        for (int p = 0; p < NBUF; ++p) stage_nt(bfrag, smem[p], p, wave, lane);
    } else {
#pragma unroll
        for (int p = 0; p < DEPTH; ++p) stage_nt(bfrag, smem[p], p, wave, lane);
    }

    for (int i = threadIdx.x; i < KCODES; i += 512)
        sb_lds[i] = -0.5f * cnorm[i];

    // ---- A-build (identical all variants) ----
    long afr[KSU];
    {
        int row = rowbase + col;
        int b = row >> 12;
        int t = row & (TDIM - 1);
        const float* xb = x + (size_t)b * (PDIM * TDIM);
#pragma unroll
        for (int ks = 0; ks < KSU; ++ks) {
            float v[8];
#pragma unroll
            for (int j = 0; j < 8; ++j) {
                int d = ks * 16 + hi2 * 8 + j;
                float f = 0.f;
                if (d < DDIM) {
                    int p  = d / WINW;
                    int w  = d - p * WINW;
                    int tt = t + w - PADW;
                    if (tt >= 0 && tt < TDIM) f = xb[p * TDIM + tt];
                }
                v[j] = f;
            }
            unsigned int lo = pack4_fp8(v[0], v[1], v[2], v[3]);
            unsigned int hi = pack4_fp8(v[4], v[5], v[6], v[7]);
            afr[ks] = (long)(((unsigned long long)hi << 32) | lo);
        }
    }

    f32x16 bs;
#pragma unroll
    for (int r = 0; r < 16; ++r) bs[r] = -3.0e38f;

    __syncthreads();   // entry drain: staged tiles resident; sb_lds visible

    for (int c = 0; c < NT32; ++c) {
        if (V != 3 && V != 5) {
            if (c > 0) {
                int rem = NT32 - 1 - c;
                if (rem >= 3)      asm volatile("s_waitcnt vmcnt(6)" ::: "memory");
                else if (rem == 2) asm volatile("s_waitcnt vmcnt(4)" ::: "memory");
                else if (rem == 1) asm volatile("s_waitcnt vmcnt(2)" ::: "memory");
                else               asm volatile("s_waitcnt vmcnt(0)" ::: "memory");
                __builtin_amdgcn_s_barrier();
                __builtin_amdgcn_sched_barrier(0);
            }
            if (c + DEPTH < NT32)
                stage_nt(bfrag, smem[(c + DEPTH) % NBUF], c + DEPTH, wave, lane);
        }

        const long* bp = (const long*)(smem[c % NBUF]) + lane;
        f32x16 acc;
#pragma unroll
        for (int r = 0; r < 16; ++r) acc[r] = 0.f;

        __builtin_amdgcn_s_setprio(1);
#pragma unroll
        for (int ks = 0; ks < KSU; ++ks) {
            if (V == 5) {
                acc = __builtin_amdgcn_mfma_f32_32x32x16_fp8_fp8(afr[ks], afr[ks], acc, 0, 0, 0);
            } else if (V == 1) {
                long bq = bp[ks * 64];
                asm volatile("" :: "v"(bq));   // keep read live (rule #17)
                acc = __builtin_amdgcn_mfma_f32_32x32x16_fp8_fp8(afr[ks], afr[ks], acc, 0, 0, 0);
            } else {
                long bq = bp[ks * 64];
                acc = __builtin_amdgcn_mfma_f32_32x32x16_fp8_fp8(afr[ks], bq, acc, 0, 0, 0);
            }
        }
        __builtin_amdgcn_s_setprio(0);

        const float sb = sb_lds[c * 32 + col];
#pragma unroll
        for (int r = 0; r < 16; ++r)
            bs[r] = fmaxf(bs[r], acc[r] + sb);
    }

#pragma unroll
    for (int m = 1; m < 32; m <<= 1)
#pragma unroll
        for (int r = 0; r < 16; ++r)
            bs[r] = fmaxf(bs[r], __shfl_xor(bs[r], m, 64));

    if (col == 0) {
        float s = 0.f;
#pragma unroll
        for (int r = 0; r < 16; ++r) s += bs[r];
        gsum[wave * 2 + hi2] = s;
    }
    __syncthreads();
    if (threadIdx.x == 0) {
        float tot = 0.f;
#pragma unroll
        for (int i = 0; i < 2 * WAVES; ++i) tot += gsum[i];
        bpart[blockIdx.x] = tot;
    }
}

__global__ __launch_bounds__(256) void finalize_k(const float* __restrict__ bpart,
                                                  const float* __restrict__ xsq_part,
                                                  float* __restrict__ out) {
    __shared__ double sm[256];
    int tid = threadIdx.x;
    sm[tid] = (double)bpart[tid];
    __syncthreads();
    for (int st = 128; st > 0; st >>= 1) {
        if (tid < st) sm[tid] += sm[tid + st];
        __syncthreads();
    }
    double S1 = sm[0];
    __syncthreads();
    sm[tid] = (double)xsq_part[tid];
    __syncthreads();
    for (int st = 128; st > 0; st >>= 1) {
        if (tid < st) sm[tid] += sm[tid + st];
        __syncthreads();
    }
    if (tid == 0)
        out[0] = (float)(0.25 * (sm[0] - 2.0 * S1) / ((double)MROWS * (double)DDIM));
}

extern "C" void kernel_launch(void* const* d_in, const int* in_sizes, int n_in,
                              void* d_out, int out_size, void* d_ws, size_t ws_size,
                              hipStream_t stream) {
    const float* x  = (const float*)d_in[0];
    const float* cb = (const float*)d_in[1];
    float* out = (float*)d_out;

    char* ws = (char*)d_ws;
    unsigned long long* bfrag = (unsigned long long*)ws;            // 512 KiB
    float* cnorm    = (float*)(ws + (512u << 10));                  // 4 KiB
    float* xsq_part = (float*)(ws + (512u << 10) + 4096);           // 1 KiB
    float* bpart    = (float*)(ws + (512u << 10) + 8192);           // 1 KiB
    float* dummy1   = (float*)(ws + (512u << 10) + 8192 + 1024);    // 1 KiB
    float* dummy3   = (float*)(ws + (512u << 10) + 8192 + 2048);    // 1 KiB
    float* dummy5   = (float*)(ws + (512u << 10) + 8192 + 3072);    // 1 KiB

    prep_bfrag_k<<<256, 256, 0, stream>>>(cb, bfrag);
    prep_cnorm_k<<<KCODES, 64, 0, stream>>>(cb, cnorm);
    xsq_k<<<256, 256, 0, stream>>>(x, xsq_part);

    vq_main_k<0><<<NBLK, 512, 0, stream>>>(x, (const unsigned char*)bfrag, cnorm, bpart);
    vq_main_k<1><<<NBLK, 512, 0, stream>>>(x, (const unsigned char*)bfrag, cnorm, dummy1);
    vq_main_k<3><<<NBLK, 512, 0, stream>>>(x, (const unsigned char*)bfrag, cnorm, dummy3);
    vq_main_k<5><<<NBLK, 512, 0, stream>>>(x, (const unsigned char*)bfrag, cnorm, dummy5);

    finalize_k<<<1, 256, 0, stream>>>(bpart, xsq_part, out);
}

// Round 17
// 94.621 us; speedup vs baseline: 2.6554x; 2.6554x over previous
//
#include <hip/hip_runtime.h>

// Problem constants
#define BDIM   16
#define PDIM   12
#define TDIM   4096
#define WINW   41
#define PADW   20
#define DDIM   492      // P*WIN
#define KCODES 1024

// fp8 16x16x32 MFMA geometry, paired-K B layout (verified in R12, absmax 0).
// R16 ablation: the 32x32 kernel's 104us was a scheduling artifact -- the
// barrier+sched_barrier(0) pin plus VGPR starvation (afr=62 at the 128 cap)
// serialized ds_read->MFMA at ~100cyc/MFMA. 16x16 halves afr (32 regs),
// acc is 4 regs/chain, and a whole tile's B (8 x b128 = 32 regs) fits in
// registers -> live ~100 < 128, no spill, and the scheduler can hoist reads.
#define KSTEPS   16                  // K-steps of 32 -> 512
#define KPAIRS   8                   // paired K-steps (b128 reads)
#define NTILES   64                  // code tiles of 16 -> 1024
#define TILE_BYTES (KPAIRS * 64 * 16)   // 8 KiB per 16-code tile
#define NCHUNK   32                  // chunks of 2 tiles
#define CHUNK_BYTES (2 * TILE_BYTES) // 16 KiB

#define WAVES      8                 // 512-thread blocks (R5-R15 best shape)
#define ROWS_WAVE  16                // one 16-row slab per wave
#define BMROWS     (WAVES * ROWS_WAVE)   // 128 rows per block
#define MROWS      (BDIM * TDIM)         // 65536
#define NBLK       (MROWS / BMROWS)      // 512 = 2 clean rounds of 1 block/CU

#define NBUF   6                    // 96 KiB staging LDS ring
#define DEPTH  4                    // prefetch distance (chunks)

typedef __attribute__((ext_vector_type(4))) float f32x4;
typedef __attribute__((ext_vector_type(2))) long  long2v;

// two f32 pairs -> 4 e4m3 bytes (RNE, saturating) via v_cvt_pk_fp8_f32
__device__ __forceinline__ unsigned int pack4_fp8(float a, float b, float c, float d) {
    int v = 0;
    v = __builtin_amdgcn_cvt_pk_fp8_f32(a, b, v, false);  // bytes 0,1
    v = __builtin_amdgcn_cvt_pk_fp8_f32(c, d, v, true);   // bytes 2,3
    return (unsigned int)v;
}

__device__ __forceinline__ long pack8_fp8(const float* v) {
    unsigned int lo = pack4_fp8(v[0], v[1], v[2], v[3]);
    unsigned int hi = pack4_fp8(v[4], v[5], v[6], v[7]);
    return (long)(((unsigned long long)hi << 32) | lo);
}

// Pre-format codebook into fp8 B-fragments for mfma_f32_16x16x32_fp8_fp8,
// PAIRED-K layout for b128 LDS reads (identical to R12, which passed):
//   entry e = (nt*KPAIRS + kp)*64 + lane holds 16 bytes:
//     long0: B[k][n], k = kp*64 +      hi*8 + j   (ks = 2kp)
//     long1: B[k][n], k = kp*64 + 32 + hi*8 + j   (ks = 2kp+1)
//   n = nt*16 + (lane&15), hi = lane>>4.
__global__ __launch_bounds__(256) void prep_bfrag_k(const float* __restrict__ cb,
                                                    long2v* __restrict__ bfrag) {
    int e    = blockIdx.x * 256 + threadIdx.x;   // 0..32767
    int lane = e & 63;
    int kp   = (e >> 6) & (KPAIRS - 1);
    int nt   = e >> 9;
    int n    = nt * 16 + (lane & 15);
    int hi   = lane >> 4;
    float v0[8], v1[8];
#pragma unroll
    for (int j = 0; j < 8; ++j) {
        int k0 = kp * 64 + hi * 8 + j;
        int k1 = k0 + 32;
        v0[j] = (k0 < DDIM) ? cb[n * DDIM + k0] : 0.f;
        v1[j] = (k1 < DDIM) ? cb[n * DDIM + k1] : 0.f;
    }
    long2v out;
    out[0] = pack8_fp8(v0);
    out[1] = pack8_fp8(v1);
    bfrag[e] = out;
}

// Exact fp32 code norms.
__global__ __launch_bounds__(64) void prep_cnorm_k(const float* __restrict__ cb,
                                                   float* __restrict__ cnorm) {
    int n = blockIdx.x;
    int lane = threadIdx.x;
    float s = 0.f;
    for (int d = lane; d < DDIM; d += 64) { float c = cb[n * DDIM + d]; s += c * c; }
#pragma unroll
    for (int m = 1; m < 64; m <<= 1) s += __shfl_xor(s, m, 64);
    if (lane == 0) cnorm[n] = s;
}

// Exact sum of ||f||^2 over all rows via window multiplicity:
// mult(tt) = 41 - max(0,20-tt) - max(0,tt-4075).
__global__ __launch_bounds__(256) void xsq_k(const float* __restrict__ x,
                                             float* __restrict__ xsq_part) {
    float s = 0.f;
    for (int i = blockIdx.x * 256 + threadIdx.x; i < BDIM * PDIM * TDIM; i += 256 * 256) {
        int tt = i & (TDIM - 1);
        int mult = WINW - max(0, PADW - tt) - max(0, tt - (TDIM - 1 - PADW));
        float v = x[i];
        s += (float)mult * v * v;
    }
#pragma unroll
    for (int m = 1; m < 64; m <<= 1) s += __shfl_xor(s, m, 64);
    __shared__ float sm[4];
    if ((threadIdx.x & 63) == 0) sm[threadIdx.x >> 6] = s;
    __syncthreads();
    if (threadIdx.x == 0) xsq_part[blockIdx.x] = sm[0] + sm[1] + sm[2] + sm[3];
}

// Stage one 16 KiB chunk (2 tiles) into LDS (async, width 16, linear order).
// 8 waves x 2 calls x 64 lanes x 16 B = 16 KiB -> 2 vmcnt slots per stage/wave.
__device__ __forceinline__ void stage_chunk(const unsigned char* __restrict__ bfrag,
                                            unsigned char* dst, int c, int wave, int lane) {
    const unsigned char* g = bfrag + (size_t)c * CHUNK_BYTES;
#pragma unroll
    for (int it = 0; it < 2; ++it) {
        int off = wave * 2048 + it * 1024;
        __builtin_amdgcn_global_load_lds(
            (const __attribute__((address_space(1))) unsigned int*)(g + off + lane * 16),
            (__attribute__((address_space(3))) unsigned int*)(dst + off),
            16, 0, 0);
    }
}

// Main sweep: 512 blocks x 8 waves x 16 rows. fp8 A-slab (32 regs) in
// registers; codes streamed through six 16 KiB LDS chunk buffers, depth-4
// prefetch, counted vmcnt ramp (6/4/2/0) + raw s_barrier at chunk edges ONLY.
// NO sched_barrier(0), NO setprio (R16: the pin serialized read->MFMA).
// Per tile: 8 x ds_read_b128 up-front (32 regs of B in flight), then 16
// MFMAs across 4 independent acc chains (acc[ks&3]) -> 8 chains/SIMD.
__global__ __launch_bounds__(512)
void vq_main_k(const float* __restrict__ x,
               const unsigned char* __restrict__ bfrag,
               const float* __restrict__ cnorm,
               float* __restrict__ bpart) {
    __shared__ __align__(16) unsigned char smem[NBUF][CHUNK_BYTES];  // 96 KiB
    __shared__ float sb_lds[KCODES];                                 // 4 KiB
    __shared__ float gsum[4 * WAVES];

    const int lane = threadIdx.x & 63;
    const int wave = threadIdx.x >> 6;
    const int col  = lane & 15;     // B/D column within 16-code tile
    const int hi   = lane >> 4;
    const int rowbase = blockIdx.x * BMROWS + wave * ROWS_WAVE;

    // Depth-4 staging kickoff; latency covered by sb-table + A-build below.
#pragma unroll
    for (int p = 0; p < DEPTH; ++p)
        stage_chunk(bfrag, smem[p], p, wave, lane);

    // Bias table: sb_lds[n] = -0.5*||c_n||^2 (4 KiB LDS)
    for (int i = threadIdx.x; i < KCODES; i += 512)
        sb_lds[i] = -0.5f * cnorm[i];

    // ---- Build fp8 A-slab: row = rowbase + col, k = ks*32 + hi*8 + j ----
    long afr[KSTEPS];
    {
        int row = rowbase + col;
        int b = row >> 12;
        int t = row & (TDIM - 1);
        const float* xb = x + (size_t)b * (PDIM * TDIM);
#pragma unroll
        for (int ks = 0; ks < KSTEPS; ++ks) {
            float v[8];
#pragma unroll
            for (int j = 0; j < 8; ++j) {
                int d = ks * 32 + hi * 8 + j;
                float f = 0.f;
                if (d < DDIM) {
                    int p  = d / WINW;
                    int w  = d - p * WINW;
                    int tt = t + w - PADW;
                    if (tt >= 0 && tt < TDIM) f = xb[p * TDIM + tt];
                }
                v[j] = f;
            }
            afr[ks] = pack8_fp8(v);
        }
    }

    float bs[4];
#pragma unroll
    for (int r = 0; r < 4; ++r) bs[r] = -3.0e38f;

    // One full drain at pipeline entry (chunks 0..3 resident; sb_lds visible).
    __syncthreads();

    for (int c = 0; c < NCHUNK; ++c) {
        if (c > 0) {
            // Retire stage(c); later stages (2 loads each) may stay in flight.
            int rem = NCHUNK - 1 - c;
            if (rem >= 3)      asm volatile("s_waitcnt vmcnt(6)" ::: "memory");
            else if (rem == 2) asm volatile("s_waitcnt vmcnt(4)" ::: "memory");
            else if (rem == 1) asm volatile("s_waitcnt vmcnt(2)" ::: "memory");
            else               asm volatile("s_waitcnt vmcnt(0)" ::: "memory");
            __builtin_amdgcn_s_barrier();   // chunk c resident; buf[(c-2)%NBUF] free
        }
        // Prefetch chunk c+DEPTH into the buffer freed at chunk c-2.
        if (c + DEPTH < NCHUNK) stage_chunk(bfrag, smem[(c + DEPTH) % NBUF], c + DEPTH, wave, lane);

#pragma unroll
        for (int tl = 0; tl < 2; ++tl) {
            const int nt = c * 2 + tl;
            const long2v* bp = (const long2v*)(smem[c % NBUF] + tl * TILE_BYTES) + lane;

            // Whole tile's B up-front: 8 x ds_read_b128 (32 VGPRs in flight).
            long2v bq[KPAIRS];
#pragma unroll
            for (int kp = 0; kp < KPAIRS; ++kp) bq[kp] = bp[kp * 64];

            f32x4 acc0 = {0.f,0.f,0.f,0.f}, acc1 = {0.f,0.f,0.f,0.f};
            f32x4 acc2 = {0.f,0.f,0.f,0.f}, acc3 = {0.f,0.f,0.f,0.f};
#pragma unroll
            for (int kp = 0; kp < KPAIRS; ++kp) {
                // ks = 2kp (chain (2kp)&3), ks = 2kp+1 (chain (2kp+1)&3)
                if ((kp & 1) == 0) {
                    acc0 = __builtin_amdgcn_mfma_f32_16x16x32_fp8_fp8(afr[2 * kp],     bq[kp][0], acc0, 0, 0, 0);
                    acc1 = __builtin_amdgcn_mfma_f32_16x16x32_fp8_fp8(afr[2 * kp + 1], bq[kp][1], acc1, 0, 0, 0);
                } else {
                    acc2 = __builtin_amdgcn_mfma_f32_16x16x32_fp8_fp8(afr[2 * kp],     bq[kp][0], acc2, 0, 0, 0);
                    acc3 = __builtin_amdgcn_mfma_f32_16x16x32_fp8_fp8(afr[2 * kp + 1], bq[kp][1], acc3, 0, 0, 0);
                }
            }

            const float sb = sb_lds[nt * 16 + col];
#pragma unroll
            for (int r = 0; r < 4; ++r) {     // D: col=lane&15, row=hi*4+r
                float s = (acc0[r] + acc1[r]) + (acc2[r] + acc3[r]) + sb;
                bs[r] = fmaxf(bs[r], s);
            }
        }
    }

    // ---- Per-row max across the 16 col-lanes (masks<16 preserve hi) ----
#pragma unroll
    for (int m = 1; m < 16; m <<= 1)
#pragma unroll
        for (int r = 0; r < 4; ++r)
            bs[r] = fmaxf(bs[r], __shfl_xor(bs[r], m, 64));

    // Lane col==0 of each 16-lane group owns rows {hi*4 + r} of the slab.
    if (col == 0) {
        float s = 0.f;
#pragma unroll
        for (int r = 0; r < 4; ++r) s += bs[r];
        gsum[wave * 4 + hi] = s;
    }
    __syncthreads();
    if (threadIdx.x == 0) {
        float tot = 0.f;
#pragma unroll
        for (int i = 0; i < 4 * WAVES; ++i) tot += gsum[i];
        bpart[blockIdx.x] = tot;
    }
}

// loss = 0.25 * (Sxx - 2*sum_blocks bpart) / (65536*492); bpart has 512 entries.
__global__ __launch_bounds__(256) void finalize_k(const float* __restrict__ bpart,
                                                  const float* __restrict__ xsq_part,
                                                  float* __restrict__ out) {
    __shared__ double sm[256];
    int tid = threadIdx.x;
    sm[tid] = (double)bpart[tid] + (double)bpart[tid + 256];
    __syncthreads();
    for (int st = 128; st > 0; st >>= 1) {
        if (tid < st) sm[tid] += sm[tid + st];
        __syncthreads();
    }
    double S1 = sm[0];
    __syncthreads();
    sm[tid] = (double)xsq_part[tid];
    __syncthreads();
    for (int st = 128; st > 0; st >>= 1) {
        if (tid < st) sm[tid] += sm[tid + st];
        __syncthreads();
    }
    if (tid == 0)
        out[0] = (float)(0.25 * (sm[0] - 2.0 * S1) / ((double)MROWS * (double)DDIM));
}

extern "C" void kernel_launch(void* const* d_in, const int* in_sizes, int n_in,
                              void* d_out, int out_size, void* d_ws, size_t ws_size,
                              hipStream_t stream) {
    const float* x  = (const float*)d_in[0];   // (16,12,4096) f32
    const float* cb = (const float*)d_in[1];   // (1024,492) f32
    float* out = (float*)d_out;

    // workspace layout (~524 KiB)
    char* ws = (char*)d_ws;
    long2v* bfrag   = (long2v*)ws;                                  // 512 KiB
    float* cnorm    = (float*)(ws + (512u << 10));                  // 4 KiB
    float* xsq_part = (float*)(ws + (512u << 10) + 4096);           // 1 KiB
    float* bpart    = (float*)(ws + (512u << 10) + 8192);           // 2 KiB

    prep_bfrag_k<<<128, 256, 0, stream>>>(cb, bfrag);
    prep_cnorm_k<<<KCODES, 64, 0, stream>>>(cb, cnorm);
    xsq_k<<<256, 256, 0, stream>>>(x, xsq_part);
    vq_main_k<<<NBLK, 512, 0, stream>>>(x, (const unsigned char*)bfrag, cnorm, bpart);
    finalize_k<<<1, 256, 0, stream>>>(bpart, xsq_part, out);
}